// Round 1
// baseline (640.345 us; speedup 1.0000x reference)
//
#include <hip/hip_runtime.h>
#include <hip/hip_bf16.h>
#include <math.h>

#define T_SEQ 4096
#define C_DIM 128
#define B_SZ  4

typedef __attribute__((ext_vector_type(8))) short short8;
typedef __attribute__((ext_vector_type(4))) float f32x4;

__device__ __forceinline__ short f2bf(float f) {
    union { float fv; unsigned u; } v; v.fv = f;
    unsigned r = v.u + 0x7fff + ((v.u >> 16) & 1);
    return (short)(r >> 16);
}

__device__ __forceinline__ float bf2f(short s) {
    union { unsigned u; float fv; } v;
    v.u = ((unsigned)(unsigned short)s) << 16;
    return v.fv;
}

__device__ __forceinline__ short8 load_f32x8_bf16(const float* p) {
    const float4* q = (const float4*)p;
    float4 a = q[0], b = q[1];
    short8 r;
    r[0] = f2bf(a.x); r[1] = f2bf(a.y); r[2] = f2bf(a.z); r[3] = f2bf(a.w);
    r[4] = f2bf(b.x); r[5] = f2bf(b.y); r[6] = f2bf(b.z); r[7] = f2bf(b.w);
    return r;
}

// ---------------------------------------------------------------------------
// Kernel 1: QKV projection. y = x @ W^T, fp32 in, bf16 out.
// One wave handles a 16-row x 128-col tile of one of {Q,K,V}.
// Q gets scale = 1/sqrt(C) * log2(e) folded in (softmax runs in exp2 domain).
// V is written transposed: Vt[b][d][t], so flash PV B-frags are contiguous.
// ---------------------------------------------------------------------------
__global__ __launch_bounds__(256) void qkv_proj(
    const float* __restrict__ x, const float* __restrict__ Wq,
    const float* __restrict__ Wk, const float* __restrict__ Wv,
    short* __restrict__ Q, short* __restrict__ K, short* __restrict__ Vt)
{
    const int tid  = threadIdx.x;
    const int lane = tid & 63;
    const int ln15 = lane & 15;
    const int quad = lane >> 4;
    const int wid  = blockIdx.x * 4 + (tid >> 6);   // [0, 3072)
    const int mat  = wid >> 10;                     // 0=Q, 1=K, 2=V
    const int rt   = wid & 1023;                    // row tile [0, 1024)
    const int m0   = rt * 16;                       // global row base

    const float* W = (mat == 0) ? Wq : (mat == 1) ? Wk : Wv;

    // A-frags: A[m = lane&15][k = quad*8 + j + 32*ks] = x[m0+m][k]
    short8 afr[4];
    const float* xrow = x + (size_t)(m0 + ln15) * C_DIM + quad * 8;
#pragma unroll
    for (int ks = 0; ks < 4; ++ks)
        afr[ks] = load_f32x8_bf16(xrow + ks * 32);

    // scale for Q: 1/sqrt(128) * log2(e)
    const float scale = (mat == 0) ? (0.08838834764831845f * 1.4426950408889634f)
                                   : 1.0f;

#pragma unroll
    for (int nt = 0; nt < 8; ++nt) {
        f32x4 acc = {0.f, 0.f, 0.f, 0.f};
        // B-frags: B[k][n] = W[n][k], n = nt*16 + lane&15, k contiguous
        const float* wrow = W + (size_t)(nt * 16 + ln15) * C_DIM + quad * 8;
#pragma unroll
        for (int ks = 0; ks < 4; ++ks) {
            short8 bfr = load_f32x8_bf16(wrow + ks * 32);
            acc = __builtin_amdgcn_mfma_f32_16x16x32_bf16(afr[ks], bfr, acc, 0, 0, 0);
        }
        // C layout: col = lane&15, row = quad*4 + r
        if (mat < 2) {
            short* dst = (mat == 0) ? Q : K;
#pragma unroll
            for (int r = 0; r < 4; ++r) {
                int row = m0 + quad * 4 + r;
                dst[(size_t)row * C_DIM + nt * 16 + ln15] = f2bf(acc[r] * scale);
            }
        } else {
            const int b  = m0 >> 12;     // row / 4096
            const int t0 = m0 & 4095;
            const int d  = nt * 16 + ln15;
#pragma unroll
            for (int r = 0; r < 4; ++r) {
                int t = t0 + quad * 4 + r;
                Vt[(((size_t)(b * C_DIM + d)) << 12) + t] = f2bf(acc[r]);
            }
        }
    }
}

// ---------------------------------------------------------------------------
// Kernel 2: causal flash attention. One wave (64-thread block) per 32 Q-rows.
// KV tiles of 32. Online softmax in exp2 domain (scale*log2e folded into Q).
// P goes C-layout -> LDS -> A-layout for the PV MFMAs.
// ---------------------------------------------------------------------------
__global__ __launch_bounds__(64) void flash_attn(
    const short* __restrict__ Q, const short* __restrict__ K,
    const short* __restrict__ Vt, float* __restrict__ out)
{
    __shared__ short Plds[32 * 40];   // 32x32 P tile, padded stride 40

    const int lane = threadIdx.x;
    const int ln15 = lane & 15;
    const int quad = lane >> 4;
    const int bid  = blockIdx.x;
    const int b    = bid & 3;
    const int qi   = 127 - (bid >> 2);   // heavy tiles dispatched first
    const int q0   = qi * 32;

    const short* Qb = Q  + (size_t)b * T_SEQ * C_DIM;
    const short* Kb = K  + (size_t)b * T_SEQ * C_DIM;
    const short* Vb = Vt + (size_t)b * C_DIM * T_SEQ;

    // Q A-frags: [mset][ks], m = lane&15 -> row q0 + ms*16 + m
    short8 qf[2][4];
#pragma unroll
    for (int ms = 0; ms < 2; ++ms) {
        const short* qrow = Qb + (size_t)(q0 + ms * 16 + ln15) * C_DIM + quad * 8;
#pragma unroll
        for (int ks = 0; ks < 4; ++ks)
            qf[ms][ks] = *(const short8*)(qrow + ks * 32);
    }

    f32x4 acc[2][8];
#pragma unroll
    for (int ms = 0; ms < 2; ++ms)
#pragma unroll
        for (int nt = 0; nt < 8; ++nt)
            acc[ms][nt] = (f32x4){0.f, 0.f, 0.f, 0.f};

    float m_i[2][4], l_i[2][4];
#pragma unroll
    for (int ms = 0; ms < 2; ++ms)
#pragma unroll
        for (int r = 0; r < 4; ++r) { m_i[ms][r] = -INFINITY; l_i[ms][r] = 0.f; }

    const int kv_end = q0 + 32;
    for (int kv = 0; kv < kv_end; kv += 32) {
        const bool need_mask = (kv + 32 > q0);   // last tile only

        // ---- S = Q @ K^T for cols [kv, kv+32) : S[ms][nt] 16x16 tiles ----
        f32x4 S[2][2];
#pragma unroll
        for (int nt = 0; nt < 2; ++nt) {
            short8 kf[4];
            const short* krow = Kb + (size_t)(kv + nt * 16 + ln15) * C_DIM + quad * 8;
#pragma unroll
            for (int ks = 0; ks < 4; ++ks)
                kf[ks] = *(const short8*)(krow + ks * 32);
#pragma unroll
            for (int ms = 0; ms < 2; ++ms) {
                f32x4 s = {0.f, 0.f, 0.f, 0.f};
#pragma unroll
                for (int ks = 0; ks < 4; ++ks)
                    s = __builtin_amdgcn_mfma_f32_16x16x32_bf16(qf[ms][ks], kf[ks], s, 0, 0, 0);
                S[ms][nt] = s;
            }
        }

        if (need_mask) {
#pragma unroll
            for (int ms = 0; ms < 2; ++ms)
#pragma unroll
                for (int nt = 0; nt < 2; ++nt)
#pragma unroll
                    for (int r = 0; r < 4; ++r) {
                        int row = q0 + ms * 16 + quad * 4 + r;
                        int col = kv + nt * 16 + ln15;
                        if (col > row) S[ms][nt][r] = -INFINITY;
                    }
        }

        // ---- online softmax (exp2 domain) ----
#pragma unroll
        for (int ms = 0; ms < 2; ++ms) {
            float mnew[4], alpha[4];
#pragma unroll
            for (int r = 0; r < 4; ++r) {
                float mx = fmaxf(S[ms][0][r], S[ms][1][r]);
                mx = fmaxf(mx, __shfl_xor(mx, 1));
                mx = fmaxf(mx, __shfl_xor(mx, 2));
                mx = fmaxf(mx, __shfl_xor(mx, 4));
                mx = fmaxf(mx, __shfl_xor(mx, 8));
                float mn = fmaxf(m_i[ms][r], mx);
                alpha[r] = exp2f(m_i[ms][r] - mn);
                mnew[r]  = mn;
                m_i[ms][r] = mn;
            }
            // P = exp2(S - mnew); write bf16 to LDS; use rounded value for l
            float prow[2][4];
#pragma unroll
            for (int nt = 0; nt < 2; ++nt)
#pragma unroll
                for (int r = 0; r < 4; ++r) {
                    float p = exp2f(S[ms][nt][r] - mnew[r]);
                    short pb = f2bf(p);
                    Plds[(ms * 16 + quad * 4 + r) * 40 + nt * 16 + ln15] = pb;
                    prow[nt][r] = bf2f(pb);
                }
#pragma unroll
            for (int r = 0; r < 4; ++r) {
                float ps = prow[0][r] + prow[1][r];
                ps += __shfl_xor(ps, 1);
                ps += __shfl_xor(ps, 2);
                ps += __shfl_xor(ps, 4);
                ps += __shfl_xor(ps, 8);
                l_i[ms][r] = l_i[ms][r] * alpha[r] + ps;
            }
            // rescale O accumulator
#pragma unroll
            for (int nt = 0; nt < 8; ++nt)
#pragma unroll
                for (int r = 0; r < 4; ++r)
                    acc[ms][nt][r] *= alpha[r];
        }

        __syncthreads();   // LDS P writes -> A-layout reads (single wave, cheap)

        // ---- P A-frags: A[m = lane&15][k = quad*8+j] ----
        short8 pa[2];
#pragma unroll
        for (int ms = 0; ms < 2; ++ms)
            pa[ms] = *(const short8*)(&Plds[(ms * 16 + ln15) * 40 + quad * 8]);

        __builtin_amdgcn_wave_barrier();   // keep next iter's LDS writes below these reads

        // ---- O += P @ V : B[k=kv][n=d] = Vt[d][kv], contiguous in kv ----
#pragma unroll
        for (int nt = 0; nt < 8; ++nt) {
            const short* vrow = Vb + (size_t)(nt * 16 + ln15) * T_SEQ + kv + quad * 8;
            short8 vf = *(const short8*)(vrow);
            acc[0][nt] = __builtin_amdgcn_mfma_f32_16x16x32_bf16(pa[0], vf, acc[0][nt], 0, 0, 0);
            acc[1][nt] = __builtin_amdgcn_mfma_f32_16x16x32_bf16(pa[1], vf, acc[1][nt], 0, 0, 0);
        }
    }

    // ---- epilogue: out = acc / l ----
#pragma unroll
    for (int ms = 0; ms < 2; ++ms) {
        float inv_l[4];
#pragma unroll
        for (int r = 0; r < 4; ++r) inv_l[r] = 1.0f / l_i[ms][r];
#pragma unroll
        for (int nt = 0; nt < 8; ++nt)
#pragma unroll
            for (int r = 0; r < 4; ++r) {
                int row = q0 + ms * 16 + quad * 4 + r;
                int col = nt * 16 + ln15;
                out[((size_t)b * T_SEQ + row) * C_DIM + col] = acc[ms][nt][r] * inv_l[r];
            }
    }
}

extern "C" void kernel_launch(void* const* d_in, const int* in_sizes, int n_in,
                              void* d_out, int out_size, void* d_ws, size_t ws_size,
                              hipStream_t stream) {
    const float* x  = (const float*)d_in[0];
    const float* Wq = (const float*)d_in[1];
    const float* Wk = (const float*)d_in[2];
    const float* Wv = (const float*)d_in[3];
    float* out = (float*)d_out;

    const size_t elems = (size_t)B_SZ * T_SEQ * C_DIM;   // 2,097,152
    short* Q  = (short*)d_ws;
    short* K  = Q + elems;
    short* Vt = K + elems;   // total 12 MB of ws

    // 3072 waves (3 mats x 1024 row-tiles), 4 waves per block
    hipLaunchKernelGGL(qkv_proj, dim3(768), dim3(256), 0, stream,
                       x, Wq, Wk, Wv, Q, K, Vt);
    // 4 batches x 128 Q-tiles of 32 rows, one wave per block
    hipLaunchKernelGGL(flash_attn, dim3(512), dim3(64), 0, stream,
                       Q, K, Vt, out);
}

// Round 2
// 282.412 us; speedup vs baseline: 2.2674x; 2.2674x over previous
//
#include <hip/hip_runtime.h>
#include <hip/hip_bf16.h>
#include <math.h>

#define T_SEQ 4096
#define C_DIM 128
#define B_SZ  4

typedef __attribute__((ext_vector_type(8))) short short8;
typedef __attribute__((ext_vector_type(4))) short short4v;
typedef __attribute__((ext_vector_type(4))) float f32x4;

__device__ __forceinline__ short f2bf(float f) {
    union { float fv; unsigned u; } v; v.fv = f;
    unsigned r = v.u + 0x7fff + ((v.u >> 16) & 1);
    return (short)(r >> 16);
}

__device__ __forceinline__ float bf2f(short s) {
    union { unsigned u; float fv; } v;
    v.u = ((unsigned)(unsigned short)s) << 16;
    return v.fv;
}

__device__ __forceinline__ short8 load_f32x8_bf16(const float* p) {
    const float4* q = (const float4*)p;
    float4 a = q[0], b = q[1];
    short8 r;
    r[0] = f2bf(a.x); r[1] = f2bf(a.y); r[2] = f2bf(a.z); r[3] = f2bf(a.w);
    r[4] = f2bf(b.x); r[5] = f2bf(b.y); r[6] = f2bf(b.z); r[7] = f2bf(b.w);
    return r;
}

// ---------------------------------------------------------------------------
// Kernel 1: QKV projection. y = x @ W^T, fp32 in, bf16 out.
// All 4 waves of a block share one W matrix (block never straddles mats):
// W is staged once into LDS in fragment-contiguous bf16 layout, so B-frag
// reads are consecutive-address ds_read_b128 and the f2bf conversion of W
// is done once per block instead of once per wave.
// ---------------------------------------------------------------------------
__global__ __launch_bounds__(256) void qkv_proj(
    const float* __restrict__ x, const float* __restrict__ Wq,
    const float* __restrict__ Wk, const float* __restrict__ Wv,
    short* __restrict__ Q, short* __restrict__ K, short* __restrict__ Vt)
{
    __shared__ short8 Wl[2048];   // 32 KB: frag-contiguous W bf16

    const int tid  = threadIdx.x;
    const int lane = tid & 63;
    const int ln15 = lane & 15;
    const int quad = lane >> 4;
    const int wid  = blockIdx.x * 4 + (tid >> 6);   // [0, 3072)
    const int mat  = wid >> 10;                     // 0=Q, 1=K, 2=V (uniform per block)
    const int rt   = wid & 1023;                    // row tile [0, 1024)
    const int m0   = rt * 16;                       // global row base

    const float* W = (mat == 0) ? Wq : (mat == 1) ? Wk : Wv;

    // Cooperative stage W -> LDS. Chunk i covers W[n][kc*8 .. kc*8+7].
    // Destination: frag (nt = n>>4, ks = kc>>2), lane = (kc&3)*16 + (n&15).
    for (int i = tid; i < 2048; i += 256) {
        int n = i >> 4, kc = i & 15;
        short8 v = load_f32x8_bf16(W + n * C_DIM + kc * 8);
        Wl[((n >> 4) * 4 + (kc >> 2)) * 64 + (kc & 3) * 16 + (n & 15)] = v;
    }

    // A-frags: A[m = lane&15][k = quad*8 + j + 32*ks] = x[m0+m][k]
    short8 afr[4];
    const float* xrow = x + (size_t)(m0 + ln15) * C_DIM + quad * 8;
#pragma unroll
    for (int ks = 0; ks < 4; ++ks)
        afr[ks] = load_f32x8_bf16(xrow + ks * 32);

    __syncthreads();

    // scale for Q: 1/sqrt(128) * log2(e)  (softmax runs in exp2 domain)
    const float scale = (mat == 0) ? (0.08838834764831845f * 1.4426950408889634f)
                                   : 1.0f;

#pragma unroll
    for (int nt = 0; nt < 8; ++nt) {
        f32x4 acc = {0.f, 0.f, 0.f, 0.f};
#pragma unroll
        for (int ks = 0; ks < 4; ++ks) {
            short8 bfr = Wl[(nt * 4 + ks) * 64 + lane];
            acc = __builtin_amdgcn_mfma_f32_16x16x32_bf16(afr[ks], bfr, acc, 0, 0, 0);
        }
        // C layout: col = lane&15, row = quad*4 + r
        if (mat < 2) {
            short* dst = (mat == 0) ? Q : K;
#pragma unroll
            for (int r = 0; r < 4; ++r) {
                int row = m0 + quad * 4 + r;
                dst[(size_t)row * C_DIM + nt * 16 + ln15] = f2bf(acc[r] * scale);
            }
        } else {
            const int b  = m0 >> 12;     // row / 4096
            const int t0 = m0 & 4095;
            const int d  = nt * 16 + ln15;
            short4v sv;
#pragma unroll
            for (int r = 0; r < 4; ++r) sv[r] = f2bf(acc[r]);
            // rows t0+quad*4 .. +3 are contiguous in Vt -> one 8B store
            *(short4v*)&Vt[(((size_t)(b * C_DIM + d)) << 12) + t0 + quad * 4] = sv;
        }
    }
}

// ---------------------------------------------------------------------------
// Kernel 2: causal flash attention, KV-split-4.
// 256-thread block = 4 waves per (b, 32-row Q-tile). Wave w handles KV tiles
// w, w+4, w+8, ... with private online-softmax state and a private LDS P
// slab (no cross-wave sync inside the loop — trip counts differ!).
// Partials are combined in LDS at the end.
// ---------------------------------------------------------------------------
__global__ __launch_bounds__(256, 4) void flash_attn(
    const short* __restrict__ Q, const short* __restrict__ K,
    const short* __restrict__ Vt, float* __restrict__ out)
{
    __shared__ short Plds[4][32 * 40];          // per-wave P tile (pad 40)
    __shared__ float mbuf[4][32], lbuf[4][32];  // per-wave m, l per row
    __shared__ float mg[32], linv[32];          // global m, 1/l per row
    __shared__ __align__(16) float Ored[32 * 128];

    const int tid  = threadIdx.x;
    const int w    = tid >> 6;
    const int lane = tid & 63;
    const int ln15 = lane & 15;
    const int quad = lane >> 4;
    const int bid  = blockIdx.x;
    const int b    = bid & 3;
    const int qi   = 127 - (bid >> 2);   // heavy tiles dispatched first
    const int q0   = qi * 32;

    const short* Qb = Q  + (size_t)b * T_SEQ * C_DIM;
    const short* Kb = K  + (size_t)b * T_SEQ * C_DIM;
    const short* Vb = Vt + (size_t)b * C_DIM * T_SEQ;
    short* Pw = &Plds[w][0];

    // Q A-frags: [mset][ks], m = lane&15 -> row q0 + ms*16 + m
    short8 qf[2][4];
#pragma unroll
    for (int ms = 0; ms < 2; ++ms) {
        const short* qrow = Qb + (size_t)(q0 + ms * 16 + ln15) * C_DIM + quad * 8;
#pragma unroll
        for (int ks = 0; ks < 4; ++ks)
            qf[ms][ks] = *(const short8*)(qrow + ks * 32);
    }

    f32x4 acc[2][8];
#pragma unroll
    for (int ms = 0; ms < 2; ++ms)
#pragma unroll
        for (int nt = 0; nt < 8; ++nt)
            acc[ms][nt] = (f32x4){0.f, 0.f, 0.f, 0.f};

    float m_i[2][4], l_i[2][4];
#pragma unroll
    for (int ms = 0; ms < 2; ++ms)
#pragma unroll
        for (int r = 0; r < 4; ++r) { m_i[ms][r] = -INFINITY; l_i[ms][r] = 0.f; }

    const int n_tiles = qi + 1;
    for (int kt = w; kt < n_tiles; kt += 4) {
        const int kv = kt * 32;
        const bool need_mask = (kv + 32 > q0);   // diagonal tile only

        // ---- S = Q @ K^T for cols [kv, kv+32) ----
        f32x4 S[2][2];
#pragma unroll
        for (int nt = 0; nt < 2; ++nt) {
            short8 kf[4];
            const short* krow = Kb + (size_t)(kv + nt * 16 + ln15) * C_DIM + quad * 8;
#pragma unroll
            for (int ks = 0; ks < 4; ++ks)
                kf[ks] = *(const short8*)(krow + ks * 32);
#pragma unroll
            for (int ms = 0; ms < 2; ++ms) {
                f32x4 s = {0.f, 0.f, 0.f, 0.f};
#pragma unroll
                for (int ks = 0; ks < 4; ++ks)
                    s = __builtin_amdgcn_mfma_f32_16x16x32_bf16(qf[ms][ks], kf[ks], s, 0, 0, 0);
                S[ms][nt] = s;
            }
        }

        if (need_mask) {
#pragma unroll
            for (int ms = 0; ms < 2; ++ms)
#pragma unroll
                for (int nt = 0; nt < 2; ++nt)
#pragma unroll
                    for (int r = 0; r < 4; ++r) {
                        int row = q0 + ms * 16 + quad * 4 + r;
                        int col = kv + nt * 16 + ln15;
                        if (col > row) S[ms][nt][r] = -INFINITY;
                    }
        }

        // ---- online softmax (exp2 domain), per-wave private state ----
#pragma unroll
        for (int ms = 0; ms < 2; ++ms) {
            float mnew[4], alpha[4];
#pragma unroll
            for (int r = 0; r < 4; ++r) {
                float mx = fmaxf(S[ms][0][r], S[ms][1][r]);
                mx = fmaxf(mx, __shfl_xor(mx, 1));
                mx = fmaxf(mx, __shfl_xor(mx, 2));
                mx = fmaxf(mx, __shfl_xor(mx, 4));
                mx = fmaxf(mx, __shfl_xor(mx, 8));
                float mn = fmaxf(m_i[ms][r], mx);
                alpha[r] = exp2f(m_i[ms][r] - mn);
                mnew[r]  = mn;
                m_i[ms][r] = mn;
            }
            float prow[2][4];
#pragma unroll
            for (int nt = 0; nt < 2; ++nt)
#pragma unroll
                for (int r = 0; r < 4; ++r) {
                    float p = exp2f(S[ms][nt][r] - mnew[r]);
                    short pb = f2bf(p);
                    Pw[(ms * 16 + quad * 4 + r) * 40 + nt * 16 + ln15] = pb;
                    prow[nt][r] = bf2f(pb);
                }
#pragma unroll
            for (int r = 0; r < 4; ++r) {
                float ps = prow[0][r] + prow[1][r];
                ps += __shfl_xor(ps, 1);
                ps += __shfl_xor(ps, 2);
                ps += __shfl_xor(ps, 4);
                ps += __shfl_xor(ps, 8);
                l_i[ms][r] = l_i[ms][r] * alpha[r] + ps;
            }
#pragma unroll
            for (int nt = 0; nt < 8; ++nt)
#pragma unroll
                for (int r = 0; r < 4; ++r)
                    acc[ms][nt][r] *= alpha[r];
        }

        // wave-local LDS producer->consumer: drain DS pipe, block reordering
        __asm__ volatile("s_waitcnt lgkmcnt(0)" ::: "memory");

        // ---- P A-frags: A[m = lane&15][k = quad*8+j] ----
        short8 pa[2];
#pragma unroll
        for (int ms = 0; ms < 2; ++ms)
            pa[ms] = *(const short8*)(&Pw[(ms * 16 + ln15) * 40 + quad * 8]);

        __builtin_amdgcn_wave_barrier();   // keep next iter's writes after these reads

        // ---- O += P @ V : B[k=kv+..][n=d] = Vt[d][kv+..] contiguous ----
#pragma unroll
        for (int nt = 0; nt < 8; ++nt) {
            const short* vrow = Vb + (size_t)(nt * 16 + ln15) * T_SEQ + kv + quad * 8;
            short8 vf = *(const short8*)(vrow);
            acc[0][nt] = __builtin_amdgcn_mfma_f32_16x16x32_bf16(pa[0], vf, acc[0][nt], 0, 0, 0);
            acc[1][nt] = __builtin_amdgcn_mfma_f32_16x16x32_bf16(pa[1], vf, acc[1][nt], 0, 0, 0);
        }
    }

    // ---- cross-wave combine ----
    if (ln15 == 0) {
#pragma unroll
        for (int ms = 0; ms < 2; ++ms)
#pragma unroll
            for (int r = 0; r < 4; ++r) {
                int row = ms * 16 + quad * 4 + r;
                mbuf[w][row] = m_i[ms][r];
                lbuf[w][row] = l_i[ms][r];
            }
    }
    __syncthreads();

    if (tid < 32) {
        float m0v = mbuf[0][tid], m1v = mbuf[1][tid];
        float m2v = mbuf[2][tid], m3v = mbuf[3][tid];
        float mx = fmaxf(fmaxf(m0v, m1v), fmaxf(m2v, m3v));
        float l = exp2f(m0v - mx) * lbuf[0][tid] + exp2f(m1v - mx) * lbuf[1][tid]
                + exp2f(m2v - mx) * lbuf[2][tid] + exp2f(m3v - mx) * lbuf[3][tid];
        mg[tid] = mx;
        linv[tid] = 1.0f / l;
    }
    __syncthreads();

    // rescale own partial to the global max
    float fw[2][4];
#pragma unroll
    for (int ms = 0; ms < 2; ++ms)
#pragma unroll
        for (int r = 0; r < 4; ++r)
            fw[ms][r] = exp2f(m_i[ms][r] - mg[ms * 16 + quad * 4 + r]);
#pragma unroll
    for (int ms = 0; ms < 2; ++ms)
#pragma unroll
        for (int nt = 0; nt < 8; ++nt)
#pragma unroll
            for (int r = 0; r < 4; ++r)
                acc[ms][nt][r] *= fw[ms][r];

    // sequential accumulation rounds into Ored
#pragma unroll
    for (int rw = 0; rw < 4; ++rw) {
        if (w == rw) {
#pragma unroll
            for (int ms = 0; ms < 2; ++ms)
#pragma unroll
                for (int nt = 0; nt < 8; ++nt)
#pragma unroll
                    for (int r = 0; r < 4; ++r) {
                        int idx = (ms * 16 + quad * 4 + r) * 128 + nt * 16 + ln15;
                        if (rw == 0) Ored[idx] = acc[ms][nt][r];
                        else         Ored[idx] += acc[ms][nt][r];
                    }
        }
        __syncthreads();
    }

    // ---- epilogue: out = Ored / l, vectorized float4 ----
    for (int i = tid; i < 1024; i += 256) {
        int row = i >> 5, c4 = i & 31;
        float4 v = ((const float4*)Ored)[i];
        float s = linv[row];
        v.x *= s; v.y *= s; v.z *= s; v.w *= s;
        ((float4*)(out + ((size_t)b * T_SEQ + q0 + row) * C_DIM))[c4] = v;
    }
}

extern "C" void kernel_launch(void* const* d_in, const int* in_sizes, int n_in,
                              void* d_out, int out_size, void* d_ws, size_t ws_size,
                              hipStream_t stream) {
    const float* x  = (const float*)d_in[0];
    const float* Wq = (const float*)d_in[1];
    const float* Wk = (const float*)d_in[2];
    const float* Wv = (const float*)d_in[3];
    float* out = (float*)d_out;

    const size_t elems = (size_t)B_SZ * T_SEQ * C_DIM;   // 2,097,152
    short* Q  = (short*)d_ws;
    short* K  = Q + elems;
    short* Vt = K + elems;   // 12 MB of ws total

    hipLaunchKernelGGL(qkv_proj, dim3(768), dim3(256), 0, stream,
                       x, Wq, Wk, Wv, Q, K, Vt);
    hipLaunchKernelGGL(flash_attn, dim3(512), dim3(256), 0, stream,
                       Q, K, Vt, out);
}

// Round 3
// 219.509 us; speedup vs baseline: 2.9172x; 1.2866x over previous
//
#include <hip/hip_runtime.h>
#include <hip/hip_bf16.h>
#include <math.h>

#define T_SEQ 4096
#define C_DIM 128
#define B_SZ  4

typedef __attribute__((ext_vector_type(8))) short short8;
typedef __attribute__((ext_vector_type(4))) short short4v;
typedef __attribute__((ext_vector_type(4))) float f32x4;

__device__ __forceinline__ short f2bf(float f) {
    union { float fv; unsigned u; } v; v.fv = f;
    unsigned r = v.u + 0x7fff + ((v.u >> 16) & 1);
    return (short)(r >> 16);
}

__device__ __forceinline__ float bf2f(short s) {
    union { unsigned u; float fv; } v;
    v.u = ((unsigned)(unsigned short)s) << 16;
    return v.fv;
}

__device__ __forceinline__ short8 load_f32x8_bf16(const float* p) {
    const float4* q = (const float4*)p;
    float4 a = q[0], b = q[1];
    short8 r;
    r[0] = f2bf(a.x); r[1] = f2bf(a.y); r[2] = f2bf(a.z); r[3] = f2bf(a.w);
    r[4] = f2bf(b.x); r[5] = f2bf(b.y); r[6] = f2bf(b.z); r[7] = f2bf(b.w);
    return r;
}

// ---------------------------------------------------------------------------
// Kernel 1: QKV projection, y = x @ W^T. fp32 in, bf16 out.
// One wave = 32 rows of one matrix. No LDS, no barriers — W is read fp32
// directly in B-frag pattern (n = row = ln15, k contiguous) and converted
// inline; plenty of waves (1536) hide the latency.
// ---------------------------------------------------------------------------
__global__ __launch_bounds__(256) void qkv_proj(
    const float* __restrict__ x, const float* __restrict__ Wq,
    const float* __restrict__ Wk, const float* __restrict__ Wv,
    short* __restrict__ Q, short* __restrict__ K, short* __restrict__ Vt)
{
    const int tid  = threadIdx.x;
    const int lane = tid & 63;
    const int ln15 = lane & 15;
    const int quad = lane >> 4;
    const int wid  = blockIdx.x * 4 + (tid >> 6);   // [0, 1536)
    const int mat  = wid >> 9;                      // 0=Q, 1=K, 2=V
    const int rt   = wid & 511;                     // 32-row tile
    const int m0   = rt * 32;

    const float* W = (mat == 0) ? Wq : (mat == 1) ? Wk : Wv;

    // A-frags for 2 row-halves: A[m=ln15][k=quad*8+j+32*ks]
    short8 afr[2][4];
#pragma unroll
    for (int ms = 0; ms < 2; ++ms) {
        const float* xrow = x + (size_t)(m0 + ms * 16 + ln15) * C_DIM + quad * 8;
#pragma unroll
        for (int ks = 0; ks < 4; ++ks)
            afr[ms][ks] = load_f32x8_bf16(xrow + ks * 32);
    }

    const float scale = (mat == 0) ? (0.08838834764831845f * 1.4426950408889634f)
                                   : 1.0f;

#pragma unroll
    for (int nt = 0; nt < 8; ++nt) {
        f32x4 acc0 = {0.f, 0.f, 0.f, 0.f};
        f32x4 acc1 = {0.f, 0.f, 0.f, 0.f};
        const float* wrow = W + (size_t)(nt * 16 + ln15) * C_DIM + quad * 8;
#pragma unroll
        for (int ks = 0; ks < 4; ++ks) {
            short8 bfr = load_f32x8_bf16(wrow + ks * 32);
            acc0 = __builtin_amdgcn_mfma_f32_16x16x32_bf16(afr[0][ks], bfr, acc0, 0, 0, 0);
            acc1 = __builtin_amdgcn_mfma_f32_16x16x32_bf16(afr[1][ks], bfr, acc1, 0, 0, 0);
        }
        // C layout: col = ln15 (= output dim d), row = quad*4 + r (= t)
        if (mat < 2) {
            short* dst = (mat == 0) ? Q : K;
#pragma unroll
            for (int r = 0; r < 4; ++r) {
                dst[(size_t)(m0 + quad * 4 + r) * C_DIM + nt * 16 + ln15]      = f2bf(acc0[r] * scale);
                dst[(size_t)(m0 + 16 + quad * 4 + r) * C_DIM + nt * 16 + ln15] = f2bf(acc1[r] * scale);
            }
        } else {
            const int b  = m0 >> 12;
            const int t0 = m0 & 4095;
            const int d  = nt * 16 + ln15;
            short4v s0, s1;
#pragma unroll
            for (int r = 0; r < 4; ++r) { s0[r] = f2bf(acc0[r]); s1[r] = f2bf(acc1[r]); }
            short* vbase = Vt + (((size_t)(b * C_DIM + d)) << 12);
            *(short4v*)&vbase[t0 + quad * 4]      = s0;
            *(short4v*)&vbase[t0 + 16 + quad * 4] = s1;
        }
    }
}

// ---------------------------------------------------------------------------
// Kernel 2: causal flash attention, transposed-S, KV-split-8.
// 512-thread block = 8 waves per (b, 32-row Q-tile); wave w takes KV tiles
// w, w+8, ... . St = K·Q^T puts softmax's kv dim into registers+quads:
// reduction = 7 VALU + 2 shuffles (was 32 shuffles). P transposes to the
// PV B-operand through a per-wave LDS slab. Partials combined at the end.
// ---------------------------------------------------------------------------
__global__ __launch_bounds__(512, 4) void flash_attn(
    const short* __restrict__ Q, const short* __restrict__ K,
    const short* __restrict__ Vt, float* __restrict__ out)
{
    __shared__ short Plds[8][32 * 40];          // per-wave Pt[q][kv], stride 40
    __shared__ float mbuf[8][32], lbuf[8][32];
    __shared__ float mg[32], linv[32];
    __shared__ __align__(16) float Ored[32 * 132];   // [q][d], stride 132

    const int tid  = threadIdx.x;
    const int w    = tid >> 6;
    const int lane = tid & 63;
    const int ln15 = lane & 15;
    const int quad = lane >> 4;
    const int bid  = blockIdx.x;
    const int b    = bid & 3;
    const int qi   = 127 - (bid >> 2);   // heavy tiles dispatched first
    const int q0   = qi * 32;

    const short* Qb = Q  + (size_t)b * T_SEQ * C_DIM;
    const short* Kb = K  + (size_t)b * T_SEQ * C_DIM;
    const short* Vb = Vt + (size_t)b * C_DIM * T_SEQ;
    short* Pw = &Plds[w][0];

    // Q B-frags: B[k][n=q], n = ln15 -> row q0 + ms*16 + ln15, k = quad*8 contig
    short8 qf[2][4];
#pragma unroll
    for (int ms = 0; ms < 2; ++ms) {
        const short* qrow = Qb + (size_t)(q0 + ms * 16 + ln15) * C_DIM + quad * 8;
#pragma unroll
        for (int ks = 0; ks < 4; ++ks)
            qf[ms][ks] = *(const short8*)(qrow + ks * 32);
    }

    // O accumulator, transposed: d = nt*16 + quad*4 + r, q = ms*16 + ln15
    f32x4 acc[2][8];
#pragma unroll
    for (int ms = 0; ms < 2; ++ms)
#pragma unroll
        for (int nt = 0; nt < 8; ++nt)
            acc[ms][nt] = (f32x4){0.f, 0.f, 0.f, 0.f};

    // per-lane online-softmax state for column q = ms*16 + ln15 (dup over quads)
    float m_i[2] = {-INFINITY, -INFINITY};
    float l_i[2] = {0.f, 0.f};

    for (int kt = w; kt <= qi; kt += 8) {
        const int kv0 = kt * 32;

        // K A-frags: A[m=kv][k], m = ln15 -> row kv0 + nt*16 + ln15
        short8 kf[2][4];
#pragma unroll
        for (int nt = 0; nt < 2; ++nt) {
            const short* krow = Kb + (size_t)(kv0 + nt * 16 + ln15) * C_DIM + quad * 8;
#pragma unroll
            for (int ks = 0; ks < 4; ++ks)
                kf[nt][ks] = *(const short8*)(krow + ks * 32);
        }

        // St[ms][nt] = K-tile(nt) · Q-tile(ms)^T : row = kv, col = q
        f32x4 St[2][2];
#pragma unroll
        for (int ms = 0; ms < 2; ++ms)
#pragma unroll
            for (int nt = 0; nt < 2; ++nt) {
                f32x4 s = {0.f, 0.f, 0.f, 0.f};
#pragma unroll
                for (int ks = 0; ks < 4; ++ks)
                    s = __builtin_amdgcn_mfma_f32_16x16x32_bf16(kf[nt][ks], qf[ms][ks], s, 0, 0, 0);
                St[ms][nt] = s;
            }

        if (kt == qi) {   // diagonal tile: mask kv > q
#pragma unroll
            for (int ms = 0; ms < 2; ++ms) {
                int qcol = q0 + ms * 16 + ln15;
#pragma unroll
                for (int nt = 0; nt < 2; ++nt)
#pragma unroll
                    for (int r = 0; r < 4; ++r)
                        if (kv0 + nt * 16 + quad * 4 + r > qcol)
                            St[ms][nt][r] = -INFINITY;
            }
        }

        // ---- online softmax: kv lives in regs (8) + quads (4) ----
#pragma unroll
        for (int ms = 0; ms < 2; ++ms) {
            float mx = St[ms][0][0];
#pragma unroll
            for (int nt = 0; nt < 2; ++nt)
#pragma unroll
                for (int r = 0; r < 4; ++r) mx = fmaxf(mx, St[ms][nt][r]);
            mx = fmaxf(mx, __shfl_xor(mx, 16));
            mx = fmaxf(mx, __shfl_xor(mx, 32));
            float mn    = fmaxf(m_i[ms], mx);
            float alpha = exp2f(m_i[ms] - mn);
            m_i[ms] = mn;

            float psum = 0.f;
#pragma unroll
            for (int nt = 0; nt < 2; ++nt) {
                short4v sv;
#pragma unroll
                for (int r = 0; r < 4; ++r) {
                    float p = exp2f(St[ms][nt][r] - mn);
                    short pb = f2bf(p);
                    sv[r] = pb;
                    psum += bf2f(pb);
                }
                // Pt[q][kv]: q = ms*16+ln15, kv = nt*16 + quad*4 .. +3
                *(short4v*)&Pw[(ms * 16 + ln15) * 40 + nt * 16 + quad * 4] = sv;
            }
            psum += __shfl_xor(psum, 16);
            psum += __shfl_xor(psum, 32);
            l_i[ms] = l_i[ms] * alpha + psum;

#pragma unroll
            for (int nt = 0; nt < 8; ++nt)
#pragma unroll
                for (int r = 0; r < 4; ++r)
                    acc[ms][nt][r] *= alpha;
        }

        // wave-local LDS producer->consumer
        __asm__ volatile("s_waitcnt lgkmcnt(0)" ::: "memory");

        // Pt B-frags: B[k=kv][n=q]: n = ln15, kv = quad*8 contig
        short8 pb[2];
#pragma unroll
        for (int ms = 0; ms < 2; ++ms)
            pb[ms] = *(const short8*)(&Pw[(ms * 16 + ln15) * 40 + quad * 8]);

        __builtin_amdgcn_wave_barrier();   // next iter's writes stay after these reads

        // Ot += Vt-tile · Pt : A[m=d][k=kv] from Vt rows (contiguous kv)
#pragma unroll
        for (int nt = 0; nt < 8; ++nt) {
            short8 vf = *(const short8*)(Vb + (size_t)(nt * 16 + ln15) * T_SEQ + kv0 + quad * 8);
            acc[0][nt] = __builtin_amdgcn_mfma_f32_16x16x32_bf16(vf, pb[0], acc[0][nt], 0, 0, 0);
            acc[1][nt] = __builtin_amdgcn_mfma_f32_16x16x32_bf16(vf, pb[1], acc[1][nt], 0, 0, 0);
        }
    }

    // ---- cross-wave combine ----
    if (quad == 0) {
        mbuf[w][ln15]      = m_i[0];
        mbuf[w][16 + ln15] = m_i[1];
        lbuf[w][ln15]      = l_i[0];
        lbuf[w][16 + ln15] = l_i[1];
    }
    __syncthreads();

    if (tid < 32) {
        float mx = -INFINITY;
#pragma unroll
        for (int ww = 0; ww < 8; ++ww) mx = fmaxf(mx, mbuf[ww][tid]);
        float l = 0.f;
#pragma unroll
        for (int ww = 0; ww < 8; ++ww) l += exp2f(mbuf[ww][tid] - mx) * lbuf[ww][tid];
        mg[tid]   = mx;
        linv[tid] = 1.0f / l;
    }
    __syncthreads();

    float fw[2];
#pragma unroll
    for (int ms = 0; ms < 2; ++ms) fw[ms] = exp2f(m_i[ms] - mg[ms * 16 + ln15]);
#pragma unroll
    for (int ms = 0; ms < 2; ++ms)
#pragma unroll
        for (int nt = 0; nt < 8; ++nt)
#pragma unroll
            for (int r = 0; r < 4; ++r)
                acc[ms][nt][r] *= fw[ms];

    // sequential accumulation into Ored[q][d]
#pragma unroll
    for (int rw = 0; rw < 8; ++rw) {
        if (w == rw) {
#pragma unroll
            for (int ms = 0; ms < 2; ++ms)
#pragma unroll
                for (int nt = 0; nt < 8; ++nt) {
                    float* dst = &Ored[(ms * 16 + ln15) * 132 + nt * 16 + quad * 4];
                    if (rw == 0) {
                        *(float4*)dst = make_float4(acc[ms][nt][0], acc[ms][nt][1],
                                                    acc[ms][nt][2], acc[ms][nt][3]);
                    } else {
                        float4 v = *(const float4*)dst;
                        v.x += acc[ms][nt][0]; v.y += acc[ms][nt][1];
                        v.z += acc[ms][nt][2]; v.w += acc[ms][nt][3];
                        *(float4*)dst = v;
                    }
                }
        }
        __syncthreads();
    }

    // ---- epilogue ----
    for (int i = tid; i < 1024; i += 512) {
        int row = i >> 5, c4 = i & 31;
        float4 v = *(const float4*)&Ored[row * 132 + c4 * 4];
        float s = linv[row];
        v.x *= s; v.y *= s; v.z *= s; v.w *= s;
        ((float4*)(out + ((size_t)b * T_SEQ + q0 + row) * C_DIM))[c4] = v;
    }
}

extern "C" void kernel_launch(void* const* d_in, const int* in_sizes, int n_in,
                              void* d_out, int out_size, void* d_ws, size_t ws_size,
                              hipStream_t stream) {
    const float* x  = (const float*)d_in[0];
    const float* Wq = (const float*)d_in[1];
    const float* Wk = (const float*)d_in[2];
    const float* Wv = (const float*)d_in[3];
    float* out = (float*)d_out;

    const size_t elems = (size_t)B_SZ * T_SEQ * C_DIM;
    short* Q  = (short*)d_ws;
    short* K  = Q + elems;
    short* Vt = K + elems;

    hipLaunchKernelGGL(qkv_proj, dim3(384), dim3(256), 0, stream,
                       x, Wq, Wk, Wv, Q, K, Vt);
    hipLaunchKernelGGL(flash_attn, dim3(512), dim3(512), 0, stream,
                       Q, K, Vt, out);
}